// Round 6
// baseline (283.252 us; speedup 1.0000x reference)
//
#include <hip/hip_runtime.h>
#include <stdint.h>

typedef __bf16 bf16x8_t __attribute__((ext_vector_type(8)));
typedef float f32x4_t __attribute__((ext_vector_type(4)));

__device__ __forceinline__ uint32_t f32_to_bf16_bits(float f) {
    union { float f; uint32_t u; } v; v.f = f;
    return (v.u + 0x7FFFu + ((v.u >> 16) & 1u)) >> 16;   // RNE, finite inputs
}

// ---------------------------------------------------------------------------
// Merged prep:
//  blocks [0,4096):    Ae[n,r]=cos(pi*2r(2n+1)/8192), Ao[n,r]=cos(pi*(2r+1)(2n+1)/8192)
//  blocks [4096,12288): Xe[q,r]=bf16(x[q,2r]), Xo[q,r]=bf16(x[q,2r+1])
// ---------------------------------------------------------------------------
__global__ void prep_kernel(const float* __restrict__ X,
                            unsigned short* __restrict__ Ae,
                            unsigned short* __restrict__ Ao,
                            unsigned short* __restrict__ Xe,
                            unsigned short* __restrict__ Xo) {
    if (blockIdx.x < 4096) {
        const int idx = blockIdx.x * 256 + threadIdx.x;   // 0..1M-1
        const int sel = idx >> 19;                        // 0=even, 1=odd matrix
        const int e   = idx & ((1 << 19) - 1);
        const int n   = e >> 8;                           // 0..2047
        const int c0  = (e & 255) << 3;                   // col start
        const uint32_t tn = (uint32_t)(2 * n + 1);
        unsigned short* dst = sel ? Ao : Ae;
        uint32_t packed[4];
#pragma unroll
        for (int jj = 0; jj < 4; ++jj) {
            uint32_t cA = (uint32_t)(c0 + 2 * jj);
            uint32_t cB = cA + 1;
            uint32_t r0 = ((2u * cA + (uint32_t)sel) * tn) & 16383u;
            uint32_t r1 = ((2u * cB + (uint32_t)sel) * tn) & 16383u;
            float v0 = __cosf((float)r0 * 3.8349519697141e-4f);   // pi/8192
            float v1 = __cosf((float)r1 * 3.8349519697141e-4f);
            packed[jj] = f32_to_bf16_bits(v0) | (f32_to_bf16_bits(v1) << 16);
        }
        *(uint4*)(dst + (size_t)n * 2048 + c0) = make_uint4(packed[0], packed[1], packed[2], packed[3]);
    } else {
        const int idx = (blockIdx.x - 4096) * 256 + threadIdx.x;   // 0..2M-1
        const int q   = idx >> 9;
        const int p0  = (idx & 511) << 3;
        const float4* src = (const float4*)(X + (size_t)q * 4096 + p0);
        float4 a = src[0];
        float4 b = src[1];
        uint2 ev, od;
        ev.x = f32_to_bf16_bits(a.x) | (f32_to_bf16_bits(a.z) << 16);
        ev.y = f32_to_bf16_bits(b.x) | (f32_to_bf16_bits(b.z) << 16);
        od.x = f32_to_bf16_bits(a.y) | (f32_to_bf16_bits(a.w) << 16);
        od.y = f32_to_bf16_bits(b.y) | (f32_to_bf16_bits(b.w) << 16);
        *(uint2*)(Xe + (size_t)q * 2048 + (p0 >> 1)) = ev;
        *(uint2*)(Xo + (size_t)q * 2048 + (p0 >> 1)) = od;
    }
}

// ---------------------------------------------------------------------------
// Fused dual-parity GEMM + butterfly epilogue.
// BK=32, DOUBLE-BUFFERED LDS (8 x 8KB = 64KB), XOR-swizzled.
//
// Swizzle (BK=32: 4 x 16B slots/row, row = 64B = 16 banks):
//   phys slot s of row r holds logical k-group g = s ^ ((r>>1)&3).
//   reads: slot = g ^ ((frow>>1)&3) -> 2-way bank aliasing (free).
// Pipeline: loads for tile k+1 issued right after the barrier, full compute
// phase before the next barrier drains them. Halves are distinct __shared__
// arrays so ds_reads of the compute half can't alias in-flight staging.
// ---------------------------------------------------------------------------
template <int STAGE>
__global__ __launch_bounds__(256, 2)
void gemm_fused_kernel(const unsigned short* __restrict__ Ae,
                       const unsigned short* __restrict__ Ao,
                       const unsigned short* __restrict__ Re,
                       const unsigned short* __restrict__ Ro,
                       unsigned short* __restrict__ Te,
                       unsigned short* __restrict__ To,
                       float* __restrict__ out) {
    constexpr int KD = 2048;
    constexpr int BK = 32;
    __shared__ __attribute__((aligned(16))) unsigned short lAe0[128 * BK];
    __shared__ __attribute__((aligned(16))) unsigned short lAe1[128 * BK];
    __shared__ __attribute__((aligned(16))) unsigned short lAo0[128 * BK];
    __shared__ __attribute__((aligned(16))) unsigned short lAo1[128 * BK];
    __shared__ __attribute__((aligned(16))) unsigned short lBe0[128 * BK];
    __shared__ __attribute__((aligned(16))) unsigned short lBe1[128 * BK];
    __shared__ __attribute__((aligned(16))) unsigned short lBo0[128 * BK];
    __shared__ __attribute__((aligned(16))) unsigned short lBo1[128 * BK];

    const int tid  = threadIdx.x;
    const int wave = tid >> 6;
    const int lane = tid & 63;

    const int tile_m = blockIdx.y << 7;   // rows of Ae/Ao: [0,2048)
    const int tile_c = blockIdx.x << 7;   // rows of Re/Ro (= C cols): [0,4096)

    f32x4_t acc_e[4][4], acc_o[4][4];
#pragma unroll
    for (int i = 0; i < 4; ++i)
#pragma unroll
        for (int j = 0; j < 4; ++j) {
            acc_e[i][j] = (f32x4_t){0.f, 0.f, 0.f, 0.f};
            acc_o[i][j] = (f32x4_t){0.f, 0.f, 0.f, 0.f};
        }

    // Staging: 512 chunks of 16B per half-buffer; phys chunk c -> row c>>2,
    // slot c&3; global source group = slot ^ ((row>>1)&3).
    const int c_base = wave << 6;
    size_t roff[2];
    int lbase[2];
#pragma unroll
    for (int t = 0; t < 2; ++t) {
        const int cl  = c_base + lane + 256 * t;
        const int row = cl >> 2;
        const int grp = (cl & 3) ^ ((cl >> 3) & 3);
        roff[t]  = (size_t)row * KD + ((size_t)grp << 3);
        lbase[t] = (c_base + 256 * t) << 3;
    }

    const unsigned short* gAe = Ae + (size_t)tile_m * KD;
    const unsigned short* gAo = Ao + (size_t)tile_m * KD;
    const unsigned short* gBe = Re + (size_t)tile_c * KD;
    const unsigned short* gBo = Ro + (size_t)tile_c * KD;

    // Fragment read addressing (swizzled).
    const int frow = lane & 15;
    const int swz  = (frow >> 1) & 3;     // row-block strides are %8==0 rows
    const int gq   = lane >> 4;           // logical 8-elem k-group
    const int slotOff = ((gq ^ swz) << 3);
    const int aRowB = ((wave >> 1) * 64 + frow) * BK;
    const int bRowB = ((wave & 1) * 64 + frow) * BK;

#define GLL(gp, lp) __builtin_amdgcn_global_load_lds( \
        (const __attribute__((address_space(1))) uint32_t*)(gp), \
        (__attribute__((address_space(3))) uint32_t*)(lp), 16, 0, 0)

#define STAGE_TO(lae, lao, lbe, lbo) do { \
    _Pragma("unroll") \
    for (int t = 0; t < 2; ++t) { \
        GLL(gAe + roff[t], &lae[lbase[t]]); \
        GLL(gAo + roff[t], &lao[lbase[t]]); \
        GLL(gBe + roff[t], &lbe[lbase[t]]); \
        GLL(gBo + roff[t], &lbo[lbase[t]]); \
    } \
    gAe += BK; gAo += BK; gBe += BK; gBo += BK; \
} while (0)

#define COMPUTE(lae, lao, lbe, lbo) do { \
    bf16x8_t af[4], bfr[4]; \
    _Pragma("unroll") \
    for (int i = 0; i < 4; ++i) af[i]  = *(const bf16x8_t*)(&lae[aRowB + i * 16 * BK + slotOff]); \
    _Pragma("unroll") \
    for (int j = 0; j < 4; ++j) bfr[j] = *(const bf16x8_t*)(&lbe[bRowB + j * 16 * BK + slotOff]); \
    _Pragma("unroll") \
    for (int i = 0; i < 4; ++i) \
        _Pragma("unroll") \
        for (int j = 0; j < 4; ++j) \
            acc_e[i][j] = __builtin_amdgcn_mfma_f32_16x16x32_bf16(af[i], bfr[j], acc_e[i][j], 0, 0, 0); \
    _Pragma("unroll") \
    for (int i = 0; i < 4; ++i) af[i]  = *(const bf16x8_t*)(&lao[aRowB + i * 16 * BK + slotOff]); \
    _Pragma("unroll") \
    for (int j = 0; j < 4; ++j) bfr[j] = *(const bf16x8_t*)(&lbo[bRowB + j * 16 * BK + slotOff]); \
    _Pragma("unroll") \
    for (int i = 0; i < 4; ++i) \
        _Pragma("unroll") \
        for (int j = 0; j < 4; ++j) \
            acc_o[i][j] = __builtin_amdgcn_mfma_f32_16x16x32_bf16(af[i], bfr[j], acc_o[i][j], 0, 0, 0); \
} while (0)

    STAGE_TO(lAe0, lAo0, lBe0, lBo0);        // preload tile 0 into half 0

    for (int kt2 = 0; kt2 < 32; ++kt2) {
        __syncthreads();                      // drains half-0 loads (aged) + half-1 consumed
        STAGE_TO(lAe1, lAo1, lBe1, lBo1);     // prefetch tile 2*kt2+1
        COMPUTE(lAe0, lAo0, lBe0, lBo0);      // compute tile 2*kt2

        __syncthreads();                      // drains half-1 loads (aged) + half-0 consumed
        if (kt2 != 31)
            STAGE_TO(lAe0, lAo0, lBe0, lBo0); // prefetch tile 2*kt2+2
        COMPUTE(lAe1, lAo1, lBe1, lBo1);      // compute tile 2*kt2+1
    }
#undef COMPUTE
#undef STAGE_TO
#undef GLL

    // C/D map: col = lane&15, row = (lane>>4)*4 + reg
    const int orow = tile_m + (wave >> 1) * 64 + ((lane >> 4) << 2);
    const int ocol = tile_c + (wave & 1) * 64 + (lane & 15);
    if (STAGE == 1) {
        unsigned short* dst = (ocol & 1) ? To : Te;   // parity fixed per thread
#pragma unroll
        for (int i = 0; i < 4; ++i)
#pragma unroll
            for (int j = 0; j < 4; ++j)
#pragma unroll
                for (int r = 0; r < 4; ++r) {
                    const int n = orow + i * 16 + r;
                    const int c = (ocol + j * 16) >> 1;
                    const float e = acc_e[i][j][r], o = acc_o[i][j][r];
                    dst[(size_t)n * 2048 + c]          = (unsigned short)f32_to_bf16_bits(e + o);
                    dst[(size_t)(4095 - n) * 2048 + c] = (unsigned short)f32_to_bf16_bits(e - o);
                }
    } else {
#pragma unroll
        for (int i = 0; i < 4; ++i)
#pragma unroll
            for (int j = 0; j < 4; ++j)
#pragma unroll
                for (int r = 0; r < 4; ++r) {
                    const int m = orow + i * 16 + r;
                    const int w = ocol + j * 16;
                    const float e = acc_e[i][j][r], o = acc_o[i][j][r];
                    out[(size_t)m * 4096 + w]          = e + o;
                    out[(size_t)(4095 - m) * 4096 + w] = e - o;
                }
    }
}

// ---------------------------------------------------------------------------
// Pipeline:
//   prep:   Ae,Ao (cosine tables) + Xe,Xo (deinterleaved bf16 x)
//   stage1: (Ae,Ao) x (Xe,Xo) -> butterfly -> Te,To (bf16, deinterleaved)
//   stage2: (Ae,Ao) x (Te,To) -> butterfly -> out (fp32)
// ws: Ae[0,8M) Ao[8,16M) Xe[16,32M) Xo[32,48M) Te[48,64M) To[64,80M)
// ---------------------------------------------------------------------------
extern "C" void kernel_launch(void* const* d_in, const int* in_sizes, int n_in,
                              void* d_out, int out_size, void* d_ws, size_t ws_size,
                              hipStream_t stream) {
    const float* x = (const float*)d_in[0];
    char* ws = (char*)d_ws;
    const size_t MB = 1024 * 1024;
    unsigned short* Ae = (unsigned short*)(ws);
    unsigned short* Ao = (unsigned short*)(ws + 8 * MB);
    unsigned short* Xe = (unsigned short*)(ws + 16 * MB);
    unsigned short* Xo = (unsigned short*)(ws + 32 * MB);
    unsigned short* Te = (unsigned short*)(ws + 48 * MB);
    unsigned short* To = (unsigned short*)(ws + 64 * MB);
    float* out = (float*)d_out;

    prep_kernel<<<12288, 256, 0, stream>>>(x, Ae, Ao, Xe, Xo);

    dim3 grid(32, 16);
    gemm_fused_kernel<1><<<grid, 256, 0, stream>>>(Ae, Ao, Xe, Xo, Te, To, nullptr);
    gemm_fused_kernel<2><<<grid, 256, 0, stream>>>(Ae, Ao, Te, To, nullptr, nullptr, out);
}